// Round 1
// baseline (239.152 us; speedup 1.0000x reference)
//
#include <hip/hip_runtime.h>
#include <hip/hip_fp16.h>

#define NLAB 30000
#define HID  1024
#define NB   256
#define NE   (NLAB - 1)

#define RECB   256               // rec-specialist blocks (pure gather)
#define ROWB   256               // row blocks (one full batch row each)
#define BLOCKS (RECB + ROWB)
#define NL4    (NLAB / 4)        // 7500 float4 per row
#define EREC   19456             // edges owned by rec blocks (76 each, contiguous)
#define KREC   (EREC / RECB)     // 76
// row blocks own NE-EREC = 10543 edges: block j takes 42 (j<47) or 41 contiguous

// float block reduce, 1024 threads (16 waves)
__device__ __forceinline__ float blockReduceSum1024(float v) {
#pragma unroll
    for (int off = 32; off > 0; off >>= 1)
        v += __shfl_down(v, off, 64);
    __shared__ float smr[16];
    const int lane = threadIdx.x & 63;
    const int wid  = threadIdx.x >> 6;
    __syncthreads();
    if (lane == 0) smr[wid] = v;
    __syncthreads();
    float r = 0.f;
    if (threadIdx.x == 0) {
#pragma unroll
        for (int i = 0; i < 16; ++i) r += smr[i];
    }
    return r;
}

__device__ __forceinline__ double blockReduceSumD256(double v) {
#pragma unroll
    for (int off = 32; off > 0; off >>= 1)
        v += __shfl_down(v, off, 64);
    __shared__ double smd[4];
    const int lane = threadIdx.x & 63;
    const int wid  = threadIdx.x >> 6;
    __syncthreads();
    if (lane == 0) smd[wid] = v;
    __syncthreads();
    double r = 0.0;
    if (threadIdx.x == 0) r = smd[0] + smd[1] + smd[2] + smd[3];
    return r;
}

__device__ __forceinline__ float sqdiff4(const float4 a, const float4 b) {
    const float dx = a.x - b.x, dy = a.y - b.y;
    const float dz = a.z - b.z, dw = a.w - b.w;
    return dx * dx + dy * dy + dz * dz + dw * dw;
}

// ---------------------------------------------------------------------------
// Barrier-free direct-to-VGPR gather.
// Block's edges [base, base+cnt) split contiguously over 16 waves.
// Indices for the wave's (<=5) edges are prefetched into lanes 0..mycnt-1
// with ONE coalesced load each, then broadcast per edge via __shfl — the
// dependent index load is off the critical path. Each edge: 8 x 1KB
// global_load_dwordx4 (lane*16B contiguous), sqdiff accumulated in regs.
// No __syncthreads anywhere: TLP across 32 waves/CU hides latency
// (vs. the old DMA rounds whose full vmcnt drain per round left in-flight
// bytes near zero ~90% of the time).
// ---------------------------------------------------------------------------
__device__ __forceinline__ float rec_direct(const float* __restrict__ params,
                                            const int* __restrict__ pidx,
                                            const int* __restrict__ cidx,
                                            int base, int cnt,
                                            int tid, int lane) {
    const int w      = tid >> 6;           // wave 0..15
    const int per    = cnt >> 4;
    const int rem    = cnt & 15;
    const int mycnt  = per + (w < rem ? 1 : 0);
    const int mybase = base + w * per + (w < rem ? w : rem);

    // lane-prefetch this wave's edge indices (mycnt <= 5)
    int pv = 0, cv = 0;
    if (lane < mycnt) {
        pv = pidx[mybase + lane];
        cv = cidx[mybase + lane];
    }

    float recs = 0.f;
    for (int k = 0; k < mycnt; ++k) {
        const int pr = __shfl(pv, k, 64);
        const int cr = __shfl(cv, k, 64);
        const float4* pa = (const float4*)params + (size_t)pr * (HID / 4) + lane;
        const float4* ca = (const float4*)params + (size_t)cr * (HID / 4) + lane;
        // 8 independent 1KB loads; offsets 0/1024/2048/3072B fold into
        // global_load imm offsets (13-bit signed covers +-4KB)
        const float4 a0 = pa[0],   b0 = ca[0];
        const float4 a1 = pa[64],  b1 = ca[64];
        const float4 a2 = pa[128], b2 = ca[128];
        const float4 a3 = pa[192], b3 = ca[192];
        recs += sqdiff4(a0, b0);
        recs += sqdiff4(a1, b1);
        recs += sqdiff4(a2, b2);
        recs += sqdiff4(a3, b3);
    }
    return recs;
}

// ---------------------------------------------------------------------------
// Phase-parallel specialization:
//   blocks [0,256):   rec specialists — barrier-free gather of 76 edges each.
//   blocks [256,512): row blocks — full batch row r=bid-256: BCE + fp16
//                     sigmoid row in LDS + prob over ALL edges; then a
//                     ~41-edge gather tail (sprob stays resident; the tail
//                     never touches LDS).
// ---------------------------------------------------------------------------
__global__ __launch_bounds__(1024, 2)
void fused_kernel(const float4* __restrict__ lg4,
                  const float4* __restrict__ tg4,
                  const float* __restrict__ params,
                  const int* __restrict__ pidx,
                  const int* __restrict__ cidx,
                  double* __restrict__ slots) {
    __shared__ __attribute__((aligned(16))) char smem[60032];
    __half* sprob = (__half*)smem;    // 30000 halves = 60000 B (row blocks)

    const int tid  = threadIdx.x;
    const int bid  = blockIdx.x;
    const int lane = tid & 63;

    float bces = 0.f, recs = 0.f, ps = 0.f;

    if (bid < RECB) {
        // ---- rec specialist: gather immediately, zero barriers ----
        recs = rec_direct(params, pidx, cidx, bid * KREC, KREC, tid, lane);
    } else {
        const int j = bid - RECB;     // row index / edge-tail sub-index
        // ---- row phase: full-row sigmoid staging + BCE ----
        {
            const float4* lrow = lg4 + (size_t)j * NL4;
            const float4* trow = tg4 + (size_t)j * NL4;
            for (int i = tid; i < NL4; i += 1024) {
                const float4 l = lrow[i];
                const float4 t = trow[i];
                const float e0 = __expf(-fabsf(l.x)), i0 = __frcp_rn(1.f + e0);
                const float e1 = __expf(-fabsf(l.y)), i1 = __frcp_rn(1.f + e1);
                const float e2 = __expf(-fabsf(l.z)), i2 = __frcp_rn(1.f + e2);
                const float e3 = __expf(-fabsf(l.w)), i3 = __frcp_rn(1.f + e3);
                const float s0 = l.x > 0.f ? i0 : 1.f - i0;
                const float s1 = l.y > 0.f ? i1 : 1.f - i1;
                const float s2 = l.z > 0.f ? i2 : 1.f - i2;
                const float s3 = l.w > 0.f ? i3 : 1.f - i3;
                sprob[4 * i + 0] = __float2half(s0);
                sprob[4 * i + 1] = __float2half(s1);
                sprob[4 * i + 2] = __float2half(s2);
                sprob[4 * i + 3] = __float2half(s3);
                // softplus(l) = max(l,0) - log(sigmoid(|l|))
                bces += fmaxf(l.x, 0.f) - __logf(i0) - l.x * t.x;
                bces += fmaxf(l.y, 0.f) - __logf(i1) - l.y * t.y;
                bces += fmaxf(l.z, 0.f) - __logf(i2) - l.z * t.z;
                bces += fmaxf(l.w, 0.f) - __logf(i3) - l.w * t.w;
            }
            __syncthreads();
            // ---- prob_reg over ALL edges from LDS ----
            for (int e = tid; e < NE; e += 1024) {
                const float d = __half2float(sprob[cidx[e]]) -
                                __half2float(sprob[pidx[e]]);
                ps += d > 0.f ? d : 0.f;
            }
            // no barrier needed: the gather tail does not touch LDS, and
            // blockReduceSum1024 begins with its own __syncthreads()
        }
        // ---- rec tail: ~41 contiguous edges ----
        const int cnt  = 41 + (j < 47 ? 1 : 0);
        const int base = EREC + 41 * j + (j < 47 ? j : 47);
        recs = rec_direct(params, pidx, cidx, base, cnt, tid, lane);
    }

    const float rb = blockReduceSum1024(bces);
    const float rr = blockReduceSum1024(recs);
    const float rp = blockReduceSum1024(ps);
    if (tid == 0) {
        slots[bid]              = (double)rb;
        slots[BLOCKS + bid]     = (double)rr;
        slots[2 * BLOCKS + bid] = (double)rp;
    }
}

// finalize: sum the 3 slot arrays, combine, write scalar
__global__ void fin_kernel(const double* __restrict__ slots,
                           float* __restrict__ out) {
    double sb = 0.0, sr = 0.0, sp = 0.0;
    for (int i = threadIdx.x; i < BLOCKS; i += 256) {
        sb += slots[i];
        sr += slots[BLOCKS + i];
        sp += slots[2 * BLOCKS + i];
    }
    sb = blockReduceSumD256(sb);
    sr = blockReduceSumD256(sr);
    sp = blockReduceSumD256(sp);
    if (threadIdx.x == 0) {
        const double bce = sb * (1.0 / ((double)NB * (double)NLAB));
        out[0] = (float)(bce + 5e-5 * sr + 1e-4 * sp);
    }
}

extern "C" void kernel_launch(void* const* d_in, const int* in_sizes, int n_in,
                              void* d_out, int out_size, void* d_ws, size_t ws_size,
                              hipStream_t stream) {
    const float* logits  = (const float*)d_in[0];
    const float* targets = (const float*)d_in[1];
    const float* params  = (const float*)d_in[2];
    const int*   pidx    = (const int*)d_in[3];
    const int*   cidx    = (const int*)d_in[4];
    double* slots = (double*)d_ws;
    float*  out   = (float*)d_out;

    fused_kernel<<<BLOCKS, 1024, 0, stream>>>(
        (const float4*)logits, (const float4*)targets, params,
        pidx, cidx, slots);
    fin_kernel<<<1, 256, 0, stream>>>(slots, out);
}